// Round 5
// baseline (37.501 us; speedup 1.0000x reference)
//
#include <hip/hip_runtime.h>

#define NB 65536
#define ND 8
#define NE 16
#define NH 80
#define NF 9
#define NV 100000
#define NIN 160

typedef __attribute__((ext_vector_type(8))) short short8;    // 8 bf16 (4 VGPRs)
typedef __attribute__((ext_vector_type(4))) float float4v;   // MFMA acc

// ws layout in 4-byte units
#define WS_W1BF   0        // bf16 fused W1, [d][n][k]: 8*80*160 ushort = 51200 u32
#define WS_B1F    51200    // 640 f32 [d][h]
#define WS_W2F    51840    // 640 f32 [d][h]
#define WS_B2F    52480    // 8 f32
#define WS_WCNT   52512    // wcnts[d][blk]: 8*256 ints (per-block per-domain counts)
#define WS_LIST   54560    // origb[d][NB]: 8*65536 ints (ragged segments)
#define WS_ARAW   578848   // araw: [d][f][NB][16] ushort = 151 MB (ragged segments)

__device__ inline unsigned short f2bf(float x) {   // RNE f32->bf16
  unsigned int u = __float_as_uint(x);
  return (unsigned short)((u + 0x7fffu + ((u >> 16) & 1u)) >> 16);
}

__device__ inline uint2 pack4(float4 v) {          // relu + pack 4 f32 -> 4 bf16
  uint2 r;
  r.x = (unsigned)f2bf(fmaxf(v.x, 0.f)) | ((unsigned)f2bf(fmaxf(v.y, 0.f)) << 16);
  r.y = (unsigned)f2bf(fmaxf(v.z, 0.f)) | ((unsigned)f2bf(fmaxf(v.w, 0.f)) << 16);
  return r;
}

template <int NFF>
__device__ inline void gather_write(const float* __restrict__ emb_feats,
                                    unsigned short* __restrict__ araw,
                                    int d, int fb, const int* idx, int loc) {
  float4 v[NFF][4];
#pragma unroll
  for (int cc = 0; cc < NFF; ++cc) {
    const float4* src =
        (const float4*)(emb_feats + ((size_t)(fb + cc) * (NV + 1) + (size_t)idx[cc]) * NE);
    v[cc][0] = src[0]; v[cc][1] = src[1]; v[cc][2] = src[2]; v[cc][3] = src[3];
  }
#pragma unroll
  for (int cc = 0; cc < NFF; ++cc) {
    uint2 a = pack4(v[cc][0]), b = pack4(v[cc][1]);
    uint2 c = pack4(v[cc][2]), e = pack4(v[cc][3]);
    unsigned short* dst = araw + (((size_t)(d * NF + fb + cc) * NB + loc) << 4);
    uint4 w0 = {a.x, a.y, b.x, b.y};
    uint4 w1 = {c.x, c.y, e.x, e.y};
    *(uint4*)dst = w0;
    *((uint4*)dst + 1) = w1;
  }
}

// k_prep: weight fusion + atomic-free bucketing + embedding gather/convert.
// 512 threads = 8 waves; 2 threads per sample (q=0 -> fields 0..4, q=1 -> 4..8;
// field 4 written twice with identical bytes - benign). Per-block counts are
// written non-atomically to wcnts[d][blk]; samples land in ragged segment
// [d][blk*256 + localrank]. No cursors, no atomics, nothing to zero-init.
__global__ __launch_bounds__(512) void k_prep(
    const int* __restrict__ pid, const int* __restrict__ feats,
    const float* __restrict__ emb_feats,
    const float* __restrict__ sw1, const float* __restrict__ dw1,
    const float* __restrict__ sb1, const float* __restrict__ db1,
    const float* __restrict__ sw2, const float* __restrict__ dw2,
    const float* __restrict__ sb2, const float* __restrict__ db2,
    const float* __restrict__ dl_b,
    unsigned int* __restrict__ w1bf, float* __restrict__ wsf,
    int* __restrict__ wcnts, int* __restrict__ origb,
    unsigned short* __restrict__ araw, float* __restrict__ out) {
  const int t = threadIdx.x;
  const int gt = blockIdx.x * 512 + t;

  // ---- weight fusion (spread over first ~100 blocks) ----
  if (gt < ND * NH * (NIN / 2)) {
    int d = gt / (NH * (NIN / 2));
    int r = gt % (NH * (NIN / 2));
    int n = r / (NIN / 2);
    int k0 = (r % (NIN / 2)) * 2;
    float a = sw1[k0 * NH + n] * dw1[d * NIN * NH + k0 * NH + n];
    float b = sw1[(k0 + 1) * NH + n] * dw1[d * NIN * NH + (k0 + 1) * NH + n];
    w1bf[gt] = (unsigned)f2bf(a) | ((unsigned)f2bf(b) << 16);
  }
  if (gt < ND * NH) {
    wsf[WS_B1F + gt] = sb1[gt % NH] + db1[gt];
    wsf[WS_W2F + gt] = sw2[gt % NH] * dw2[gt];
  }
  if (gt < ND) wsf[WS_B2F + gt] = sb2[0] + db2[gt];

  // ---- bucketing: 256 samples/block, 2 threads/sample ----
  const int s = t >> 1, q = t & 1;
  const int b = blockIdx.x * 256 + s;
  const int p = pid[b];
  if (p == 0 && q == 0) out[b] = dl_b[0];  // padding: e_pid row zeros -> dl_b exactly

  const int fb = q * 4;  // fields 0..4 / 4..8
  int idx[5];
#pragma unroll
  for (int j = 0; j < 5; ++j) idx[j] = feats[b * NF + fb + j];

  const int wave = t >> 6, lane = t & 63;
  __shared__ int wcnt[8][ND], wbase[8][ND];
  int rank = 0;
#pragma unroll
  for (int d = 0; d < ND; ++d) {
    unsigned long long m = __ballot(p == d + 1 && q == 0);
    if (lane == 0) wcnt[wave][d] = (int)__popcll(m);
    if (p == d + 1) rank = (int)__popcll(m & ((1ull << (lane & 62)) - 1ull));
  }
  __syncthreads();
  if (t < ND) {
    int acc = 0;
    for (int w = 0; w < 8; ++w) { wbase[w][t] = acc; acc += wcnt[w][t]; }
    wcnts[t * 256 + blockIdx.x] = acc;   // per-block total for this domain
  }
  __syncthreads();

  if (p > 0) {
    const int d = p - 1;
    const int loc = blockIdx.x * 256 + wbase[wave][d] + rank;
    if (q == 0) origb[(size_t)d * NB + loc] = b;
    gather_write<5>(emb_feats, araw, d, fb, idx, loc);
  }
}

// k_main: per (domain, group-of-64). Scan of 256 segment counts -> binary
// search maps global rank -> ragged position; A read dense/coalesced from araw.
// MFMA 16x16x32 bf16, layer-2 fused in epilogue.
__global__ __launch_bounds__(256) void k_main(
    const float* __restrict__ emb_pid, const float* __restrict__ dl_w,
    const float* __restrict__ dl_b, const unsigned int* __restrict__ w1bf,
    const float* __restrict__ wsf, const int* __restrict__ wcnts,
    const int* __restrict__ origb, const unsigned short* __restrict__ araw,
    float* __restrict__ out) {
  const int d = blockIdx.x & 7;
  const int widx = blockIdx.x >> 3;
  const int t = threadIdx.x, wave = t >> 6, lane = t & 63;

  __shared__ unsigned short sA[64][168];   // 21504 B
  __shared__ unsigned short sB[80][168];   // 26880 B
  __shared__ int spfx[256];
  __shared__ int sPos[64], sOrig[64];
  __shared__ int wsum[4];
  __shared__ int stot;

  // stage fused W1 (bf16 [n][k]) into LDS
  const unsigned int* __restrict__ wb = w1bf + d * (NH * (NIN / 2));
  for (int i = t; i < NH * (NIN / 2); i += 256) {
    int n = i / (NIN / 2), kp = i % (NIN / 2);
    ((unsigned int*)&sB[n][0])[kp] = wb[i];
  }

  // exclusive scan of the 256 segment counts (shfl within wave, LDS across)
  int v = wcnts[d * 256 + t];
  int x = v;
#pragma unroll
  for (int sft = 1; sft < 64; sft <<= 1) {
    int y = __shfl_up(x, sft);
    if (lane >= sft) x += y;
  }
  if (lane == 63) wsum[wave] = x;
  __syncthreads();
  int woff = 0;
  for (int w = 0; w < wave; ++w) woff += wsum[w];
  spfx[t] = x - v + woff;
  if (t == 255) stot = x + woff;
  __syncthreads();
  const int c = stot;
  if (widx * 64 >= c) return;   // block-uniform

  // rank -> ragged position (binary search over segment starts)
  if (t < 64) {
    int r = widx * 64 + t;
    int rr = r < c ? r : c - 1;          // clamp padding rows to a valid slot
    int lo = 0, hi = 255;
    while (lo < hi) {
      int mid = (lo + hi + 1) >> 1;
      if (spfx[mid] <= rr) lo = mid; else hi = mid - 1;
    }
    int pos = lo * 256 + (rr - spfx[lo]);
    sPos[t] = pos;
    sOrig[t] = origb[(size_t)d * NB + pos];
  }

  // bucket-uniform hoists: domain logit + relu'd e_pid row + per-lane b1/w2
  float dlacc = dl_b[0];
  unsigned int ep[8];
  {
    const float* __restrict__ row = emb_pid + (d + 1) * NE;
#pragma unroll
    for (int i = 0; i < NE; i += 2) {
      float x0 = fmaxf(row[i], 0.f), x1 = fmaxf(row[i + 1], 0.f);
      dlacc = fmaf(x0, dl_w[i], dlacc);
      dlacc = fmaf(x1, dl_w[i + 1], dlacc);
      ep[i >> 1] = (unsigned)f2bf(x0) | ((unsigned)f2bf(x1) << 16);
    }
  }
  const float b2 = wsf[WS_B2F + d];
  float b1l[5], w2l[5];
#pragma unroll
  for (int nt = 0; nt < 5; ++nt) {
    b1l[nt] = wsf[WS_B1F + d * NH + nt * 16 + (lane & 15)];
    w2l[nt] = wsf[WS_W2F + d * NH + nt * 16 + (lane & 15)];
  }
  __syncthreads();   // sPos/sOrig ready

  // A staging: e_pid columns + dense 16B chunks from araw (f-major, coalesced)
  if (t < 128) {
    int ss = t >> 1, qq = t & 1;
    unsigned int* dst = (unsigned int*)&sA[ss][0];
#pragma unroll
    for (int j = 0; j < 4; ++j) dst[qq * 4 + j] = ep[qq * 4 + j];
  }
  for (int i = t; i < 64 * NF * 2; i += 256) {
    int h = i & 1;
    int rest = i >> 1;
    int f = rest >> 6, ss = rest & 63;
    const uint4* src =
        (const uint4*)(araw + (((size_t)(d * NF + f) * NB + sPos[ss]) << 4)) + h;
    *(uint4*)&sA[ss][16 + f * 16 + h * 8] = *src;
  }
  __syncthreads();

  // MFMA: A lane l -> row l&15, k=(l>>4)*8+e ; B lane l -> col l&15
  float4v acc[5];
#pragma unroll
  for (int nt = 0; nt < 5; ++nt)
    acc[nt] = (float4v){b1l[nt], b1l[nt], b1l[nt], b1l[nt]};
  const int arow = wave * 16 + (lane & 15);
  const int koff = (lane >> 4) * 8;
#pragma unroll
  for (int ks = 0; ks < 5; ++ks) {
    short8 af = *(const short8*)&sA[arow][ks * 32 + koff];
#pragma unroll
    for (int nt = 0; nt < 5; ++nt) {
      short8 bf = *(const short8*)&sB[nt * 16 + (lane & 15)][ks * 32 + koff];
      acc[nt] = __builtin_amdgcn_mfma_f32_16x16x32_bf16(af, bf, acc[nt], 0, 0, 0);
    }
  }

  // layer 2: relu(h) . w2, reduce across the 16-lane n-groups
  float pr[4];
#pragma unroll
  for (int r = 0; r < 4; ++r) {
    float a2 = 0.f;
#pragma unroll
    for (int nt = 0; nt < 5; ++nt) a2 = fmaf(fmaxf(acc[nt][r], 0.f), w2l[nt], a2);
    pr[r] = a2;
  }
#pragma unroll
  for (int r = 0; r < 4; ++r) {
    pr[r] += __shfl_xor(pr[r], 1);
    pr[r] += __shfl_xor(pr[r], 2);
    pr[r] += __shfl_xor(pr[r], 4);
    pr[r] += __shfl_xor(pr[r], 8);
  }
  if ((lane & 15) == 0) {
    int srow = wave * 16 + (lane >> 4) * 4;
#pragma unroll
    for (int r = 0; r < 4; ++r) {
      int kk = widx * 64 + srow + r;
      if (kk < c) out[sOrig[srow + r]] = pr[r] + b2 + dlacc;
    }
  }
}

extern "C" void kernel_launch(void* const* d_in, const int* in_sizes, int n_in,
                              void* d_out, int out_size, void* d_ws, size_t ws_size,
                              hipStream_t stream) {
  const int*   pid      = (const int*)d_in[0];
  const int*   feats    = (const int*)d_in[1];
  const float* emb_pid  = (const float*)d_in[2];
  const float* emb_f    = (const float*)d_in[3];
  const float* sw1      = (const float*)d_in[4];
  const float* dw1      = (const float*)d_in[5];
  const float* sb1      = (const float*)d_in[6];
  const float* db1      = (const float*)d_in[7];
  const float* sw2      = (const float*)d_in[8];
  const float* dw2      = (const float*)d_in[9];
  const float* sb2      = (const float*)d_in[10];
  const float* db2      = (const float*)d_in[11];
  const float* dl_w     = (const float*)d_in[12];
  const float* dl_b     = (const float*)d_in[13];
  float* out = (float*)d_out;
  float* wsf = (float*)d_ws;
  int*   wsi = (int*)d_ws;
  unsigned int* w1bf = (unsigned int*)d_ws;
  int* wcnts = wsi + WS_WCNT;
  int* origb = wsi + WS_LIST;
  unsigned short* araw = (unsigned short*)(wsi + WS_ARAW);

  k_prep<<<256, 512, 0, stream>>>(pid, feats, emb_f, sw1, dw1, sb1, db1, sw2, dw2,
                                  sb2, db2, dl_b, w1bf, wsf, wcnts, origb, araw, out);
  k_main<<<1024, 256, 0, stream>>>(emb_pid, dl_w, dl_b, w1bf, wsf, wcnts, origb,
                                   araw, out);
}

// Round 6
// 29.386 us; speedup vs baseline: 1.2761x; 1.2761x over previous
//
#include <hip/hip_runtime.h>

#define NB 65536
#define ND 8
#define NE 16
#define NH 80
#define NF 9
#define NV 100000
#define NIN 160

typedef __attribute__((ext_vector_type(8))) short short8;    // 8 bf16 (4 VGPRs)
typedef __attribute__((ext_vector_type(4))) float float4v;   // MFMA acc

// ws layout in 4-byte units
#define WS_W1BF   0        // bf16 fused W1, [d][n][k]: 8*80*160 ushort = 51200 u32
#define WS_B1F    51200    // 640 f32 [d][h]
#define WS_W2F    51840    // 640 f32 [d][h]
#define WS_B2F    52480    // 8 f32
#define WS_WCNT   52512    // wcnts[d][blk]: 8*256 ints (per-block per-domain counts)
#define WS_ORIG   54560    // origb[d][NB]: 8*65536 ints (ragged segments)
#define WS_FOFF   578848   // foffs[d][f][NB]: 8*9*65536 ints (element offsets)

__device__ inline unsigned short f2bf(float x) {   // RNE f32->bf16
  unsigned int u = __float_as_uint(x);
  return (unsigned short)((u + 0x7fffu + ((u >> 16) & 1u)) >> 16);
}

// k_fill: weight fusion + atomic-free ballot bucketing. Per block, per domain:
// non-atomic count to wcnts[d][blk]; each sample lands at ragged position
// blk*256 + localrank in segment d. Writes origb (sample id) and foffs (the 9
// precomputed embedding element-offsets, field-major) - metadata only, no data.
__global__ __launch_bounds__(256) void k_fill(
    const int* __restrict__ pid, const int* __restrict__ feats,
    const float* __restrict__ sw1, const float* __restrict__ dw1,
    const float* __restrict__ sb1, const float* __restrict__ db1,
    const float* __restrict__ sw2, const float* __restrict__ dw2,
    const float* __restrict__ sb2, const float* __restrict__ db2,
    const float* __restrict__ dl_b,
    unsigned int* __restrict__ w1bf, float* __restrict__ wsf,
    int* __restrict__ wcnts, int* __restrict__ origb, int* __restrict__ foffs,
    float* __restrict__ out) {
  const int t = threadIdx.x;
  const int gt = blockIdx.x * 256 + t;

  // ---- weight fusion (spread across blocks; independent of bucketing) ----
  if (gt < ND * NH * (NIN / 2)) {          // one uint = 2 consecutive k of W1bf[d][n][k]
    int d = gt / (NH * (NIN / 2));
    int r = gt % (NH * (NIN / 2));
    int n = r / (NIN / 2);
    int k0 = (r % (NIN / 2)) * 2;
    float a = sw1[k0 * NH + n] * dw1[d * NIN * NH + k0 * NH + n];
    float b = sw1[(k0 + 1) * NH + n] * dw1[d * NIN * NH + (k0 + 1) * NH + n];
    w1bf[gt] = (unsigned)f2bf(a) | ((unsigned)f2bf(b) << 16);
  }
  if (gt < ND * NH) {
    wsf[WS_B1F + gt] = sb1[gt % NH] + db1[gt];
    wsf[WS_W2F + gt] = sw2[gt % NH] * dw2[gt];
  }
  if (gt < ND) wsf[WS_B2F + gt] = sb2[0] + db2[gt];

  // ---- bucketing: 1 thread per sample ----
  const int b = gt;
  const int p = pid[b];
  if (p == 0) out[b] = dl_b[0];  // padding: e_pid row zeros -> logits = dl_b exactly

  int idx[NF];
#pragma unroll
  for (int f = 0; f < NF; ++f) idx[f] = feats[b * NF + f];

  const int wave = t >> 6, lane = t & 63;
  __shared__ int wcnt[4][ND], wbase[4][ND];
  int rank = 0;
#pragma unroll
  for (int d = 0; d < ND; ++d) {
    unsigned long long m = __ballot(p == d + 1);
    if (lane == 0) wcnt[wave][d] = (int)__popcll(m);
    if (p == d + 1) rank = (int)__popcll(m & ((1ull << lane) - 1ull));
  }
  __syncthreads();
  if (t < ND) {
    int acc = 0;
    for (int w = 0; w < 4; ++w) { wbase[w][t] = acc; acc += wcnt[w][t]; }
    wcnts[t * 256 + blockIdx.x] = acc;   // per-block total for this domain
  }
  __syncthreads();

  if (p > 0) {
    const int d = p - 1;
    const int loc = blockIdx.x * 256 + wbase[wave][d] + rank;
    origb[d * NB + loc] = b;
#pragma unroll
    for (int f = 0; f < NF; ++f)
      foffs[(d * NF + f) * NB + loc] = (f * (NV + 1) + idx[f]) * NE;
  }
}

// k_main: per (domain, group-of-64). Scan the 256 segment counts -> binary
// search maps global rank -> ragged position -> read precomputed offsets ->
// gather embeddings -> relu/bf16 -> LDS -> MFMA 16x16x32, layer-2 fused.
__global__ __launch_bounds__(256) void k_main(
    const float* __restrict__ emb_pid, const float* __restrict__ emb_feats,
    const float* __restrict__ dl_w, const float* __restrict__ dl_b,
    const unsigned int* __restrict__ w1bf, const float* __restrict__ wsf,
    const int* __restrict__ wcnts, const int* __restrict__ origb,
    const int* __restrict__ foffs, float* __restrict__ out) {
  const int d = blockIdx.x & 7;
  const int widx = blockIdx.x >> 3;
  const int t = threadIdx.x, wave = t >> 6, lane = t & 63;

  __shared__ unsigned short sA[64][168];   // 21504 B
  __shared__ unsigned short sB[80][168];   // 26880 B
  __shared__ int spfx[256];
  __shared__ int sPos[64], sOrig[64];
  __shared__ int wsum[4];

  // stage fused W1 (bf16 [n][k]) into LDS - independent of everything below
  const unsigned int* __restrict__ wb = w1bf + d * (NH * (NIN / 2));
  for (int i = t; i < NH * (NIN / 2); i += 256) {
    int n = i / (NIN / 2), kp = i % (NIN / 2);
    ((unsigned int*)&sB[n][0])[kp] = wb[i];
  }

  // exclusive scan of the 256 segment counts
  int v = wcnts[d * 256 + t];
  int x = v;
#pragma unroll
  for (int sft = 1; sft < 64; sft <<= 1) {
    int y = __shfl_up(x, sft);
    if (lane >= sft) x += y;
  }
  if (lane == 63) wsum[wave] = x;
  __syncthreads();
  int woff = 0;
  for (int w = 0; w < wave; ++w) woff += wsum[w];
  spfx[t] = x - v + woff;
  const int c = wsum[0] + wsum[1] + wsum[2] + wsum[3];
  __syncthreads();   // spfx visible

  // bucket-uniform hoists (register-only, off the memory critical path)
  float dlacc = dl_b[0];
  unsigned int ep[8];
  {
    const float* __restrict__ row = emb_pid + (d + 1) * NE;
#pragma unroll
    for (int i = 0; i < NE; i += 2) {
      float x0 = fmaxf(row[i], 0.f), x1 = fmaxf(row[i + 1], 0.f);
      dlacc = fmaf(x0, dl_w[i], dlacc);
      dlacc = fmaf(x1, dl_w[i + 1], dlacc);
      ep[i >> 1] = (unsigned)f2bf(x0) | ((unsigned)f2bf(x1) << 16);
    }
  }
  const float b2 = wsf[WS_B2F + d];
  float b1l[5], w2l[5];
#pragma unroll
  for (int nt = 0; nt < 5; ++nt) {
    b1l[nt] = wsf[WS_B1F + d * NH + nt * 16 + (lane & 15)];
    w2l[nt] = wsf[WS_W2F + d * NH + nt * 16 + (lane & 15)];
  }

  for (int g = widx; g * 64 < c; g += 128) {
    // rank -> ragged position (binary search over segment starts)
    if (t < 64) {
      int rr = g * 64 + t;
      if (rr >= c) rr = c - 1;            // clamp padding rows to a valid slot
      int lo = 0, hi = 255;
      while (lo < hi) {
        int mid = (lo + hi + 1) >> 1;
        if (spfx[mid] <= rr) lo = mid; else hi = mid - 1;
      }
      sPos[t] = lo * 256 + (rr - spfx[lo]);
      sOrig[t] = origb[d * NB + sPos[t]];
    }
    __syncthreads();   // sPos ready

    // gather: 4 threads/sample; offsets read directly (4 dup lanes broadcast)
    const int s = t >> 2, q = t & 3;
    const int pos = sPos[s];
    int off[NF];
#pragma unroll
    for (int f = 0; f < NF; ++f) off[f] = foffs[(d * NF + f) * NB + pos];
    float4 vv[NF];
#pragma unroll
    for (int f = 0; f < NF; ++f)
      vv[f] = ((const float4*)(emb_feats + (size_t)off[f]))[q];
    if (q < 2) {  // e_pid columns 0..15 (bucket-uniform row)
      unsigned int* dst = (unsigned int*)&sA[s][0];
#pragma unroll
      for (int j = 0; j < 4; ++j) dst[q * 4 + j] = ep[q * 4 + j];
    }
#pragma unroll
    for (int f = 0; f < NF; ++f) {
      unsigned int p0 = (unsigned)f2bf(fmaxf(vv[f].x, 0.f)) |
                        ((unsigned)f2bf(fmaxf(vv[f].y, 0.f)) << 16);
      unsigned int p1 = (unsigned)f2bf(fmaxf(vv[f].z, 0.f)) |
                        ((unsigned)f2bf(fmaxf(vv[f].w, 0.f)) << 16);
      unsigned int* dst = (unsigned int*)&sA[s][16 + f * 16];
      dst[q * 2] = p0;
      dst[q * 2 + 1] = p1;
    }
    __syncthreads();

    // MFMA: A lane l -> row l&15, k=(l>>4)*8+e ; B lane l -> col l&15
    float4v acc[5];
#pragma unroll
    for (int nt = 0; nt < 5; ++nt)
      acc[nt] = (float4v){b1l[nt], b1l[nt], b1l[nt], b1l[nt]};
    const int arow = wave * 16 + (lane & 15);
    const int koff = (lane >> 4) * 8;
#pragma unroll
    for (int ks = 0; ks < 5; ++ks) {
      short8 af = *(const short8*)&sA[arow][ks * 32 + koff];
#pragma unroll
      for (int nt = 0; nt < 5; ++nt) {
        short8 bf = *(const short8*)&sB[nt * 16 + (lane & 15)][ks * 32 + koff];
        acc[nt] = __builtin_amdgcn_mfma_f32_16x16x32_bf16(af, bf, acc[nt], 0, 0, 0);
      }
    }

    // layer 2: relu(h) . w2, reduce across the 16-lane n-groups
    float pr[4];
#pragma unroll
    for (int r = 0; r < 4; ++r) {
      float a2 = 0.f;
#pragma unroll
      for (int nt = 0; nt < 5; ++nt) a2 = fmaf(fmaxf(acc[nt][r], 0.f), w2l[nt], a2);
      pr[r] = a2;
    }
#pragma unroll
    for (int r = 0; r < 4; ++r) {
      pr[r] += __shfl_xor(pr[r], 1);
      pr[r] += __shfl_xor(pr[r], 2);
      pr[r] += __shfl_xor(pr[r], 4);
      pr[r] += __shfl_xor(pr[r], 8);
    }
    if ((lane & 15) == 0) {
      int srow = wave * 16 + (lane >> 4) * 4;
#pragma unroll
      for (int r = 0; r < 4; ++r) {
        int kk = g * 64 + srow + r;
        if (kk < c) out[sOrig[srow + r]] = pr[r] + b2 + dlacc;
      }
    }
    __syncthreads();   // before next iteration overwrites sPos/sA
  }
}

extern "C" void kernel_launch(void* const* d_in, const int* in_sizes, int n_in,
                              void* d_out, int out_size, void* d_ws, size_t ws_size,
                              hipStream_t stream) {
  const int*   pid      = (const int*)d_in[0];
  const int*   feats    = (const int*)d_in[1];
  const float* emb_pid  = (const float*)d_in[2];
  const float* emb_f    = (const float*)d_in[3];
  const float* sw1      = (const float*)d_in[4];
  const float* dw1      = (const float*)d_in[5];
  const float* sb1      = (const float*)d_in[6];
  const float* db1      = (const float*)d_in[7];
  const float* sw2      = (const float*)d_in[8];
  const float* dw2      = (const float*)d_in[9];
  const float* sb2      = (const float*)d_in[10];
  const float* db2      = (const float*)d_in[11];
  const float* dl_w     = (const float*)d_in[12];
  const float* dl_b     = (const float*)d_in[13];
  float* out = (float*)d_out;
  float* wsf = (float*)d_ws;
  int*   wsi = (int*)d_ws;
  unsigned int* w1bf = (unsigned int*)d_ws;
  int* wcnts = wsi + WS_WCNT;
  int* origb = wsi + WS_ORIG;
  int* foffs = wsi + WS_FOFF;

  k_fill<<<NB / 256, 256, 0, stream>>>(pid, feats, sw1, dw1, sb1, db1, sw2, dw2,
                                       sb2, db2, dl_b, w1bf, wsf, wcnts, origb,
                                       foffs, out);
  k_main<<<1024, 256, 0, stream>>>(emb_pid, emb_f, dl_w, dl_b, w1bf, wsf,
                                   wcnts, origb, foffs, out);
}